// Round 11
// baseline (67.619 us; speedup 1.0000x reference)
//
#include <hip/hip_runtime.h>
#include <hip/hip_bf16.h>

// out[d,t] = (sum_j exp(s[t,j]) * u[j,d]) / (sum_j exp(s[t,j]))
// Fused exp-GEMM, B staged in LDS.
// R11: D-SPLIT — each block computes HALF of D (64 cols / 4 N-frags) for 256
// rows, so B-half = 512x64 bf16 = 64KB LDS -> 2 blocks/CU -> 4 waves/SIMD
// (was 2). s is requested by both halves of a row-group, but bid = h*256+rg
// puts both on the SAME XCD (rg mod 8), co-resident and time-aligned, so the
// second reader hits L2/L3 and HBM s-traffic stays ~1x. exp is computed twice
// (hidden under memory). Per-output arithmetic identical -> absmax must stay
// exactly 0.00390625. Keeps R10's depth-6 cross-panel prefetch, 2-iter fences,
// v_cvt_pk_bf16_f32 pack.

constexpr int T_DIM = 65536;
constexpr int J_DIM = 512;
constexpr int D_DIM = 128;
constexpr int KK_STEPS = J_DIM / 32;   // 16
constexpr int NFRAG = 4;               // 4 N-fragments = 64 of 128 d-cols
constexpr int PF_DEPTH = 6;            // s-load prefetch depth (iterations)
constexpr int BP_ELEMS = KK_STEPS * NFRAG * 64;   // s16x8 elements = 4096 (64KB)

typedef __attribute__((ext_vector_type(4))) float  f32x4;
typedef __attribute__((ext_vector_type(4))) int    i32x4;
typedef __attribute__((ext_vector_type(8))) short  s16x8;
typedef __attribute__((ext_vector_type(8))) __bf16 bf16x8;

__device__ __forceinline__ short f2bf_rne(float f) {
    unsigned u = __builtin_bit_cast(unsigned, f);
    u += 0x7fffu + ((u >> 16) & 1u);   // round-to-nearest-even
    return (short)(u >> 16);
}

__device__ __forceinline__ int cvt_pk_bf16(float lo, float hi) {
    int r;
    asm("v_cvt_pk_bf16_f32 %0, %1, %2" : "=v"(r) : "v"(lo), "v"(hi));
    return r;   // r[15:0]=bf16(lo), r[31:16]=bf16(hi), RNE
}

__global__ __launch_bounds__(512, 4) void c2q_main(const float* __restrict__ sm,
                                                   const float* __restrict__ u,
                                                   float* __restrict__ out) {
    __shared__ s16x8 bsh[BP_ELEMS];    // [kk][nf][lane] — 65536 bytes

    const int tid  = threadIdx.x;
    const int l    = tid & 63;
    const int w    = tid >> 6;        // wave 0..7
    const int lmod = l & 15;
    const int lh   = l >> 4;          // 0..3
    const int bid  = blockIdx.x;
    const int h    = bid >> 8;        // d-half 0/1   (bid = h*256 + rg)
    const int rg   = bid & 255;       // row-group
    const int d0   = h * 64;
    const int r0   = rg * 256 + w * 16;          // panel-0 first t-row

    // A-fragment sources: lane holds row r0+lmod, k = kk*32 + 8*lh + i.
    const float* sp0 = sm + (size_t)(r0 + lmod) * J_DIM + lh * 8;
    const float* sp1 = sp0 + 128 * J_DIM;        // panel-1 (r0+128)

    // ---- prologue: prefetch global iterations 0..5 (panel 0, kk 0..5) ----
    f32x4 sbuf[PF_DEPTH][2];
#pragma unroll
    for (int p = 0; p < PF_DEPTH; ++p) {
        sbuf[p][0] = *reinterpret_cast<const f32x4*>(sp0 + p * 32);
        sbuf[p][1] = *reinterpret_cast<const f32x4*>(sp0 + p * 32 + 4);
    }

    // ---- B gather-fill straight from u (L2-resident), this block's d-half ----
    // element e: lane=e&63, nf=(e>>6)&3, kk=e>>8;
    //   d = d0 + nf*16 + (e&15), k0 = kk*32 + 8*((e>>4)&3); pack 8 bf16.
#pragma unroll 4
    for (int it = 0; it < BP_ELEMS / 512; ++it) {
        int e  = it * 512 + tid;
        int d  = d0 + ((e >> 6) & (NFRAG - 1)) * 16 + (e & 15);
        int k0 = (e >> 8) * 32 + 8 * ((e >> 4) & 3);
        const float* up = u + (size_t)k0 * D_DIM + d;
        s16x8 o;
#pragma unroll
        for (int i = 0; i < 8; ++i)
            o[i] = f2bf_rne(up[(size_t)i * D_DIM]);
        bsh[e] = o;
    }
    __syncthreads();

#pragma unroll
    for (int p = 0; p < 2; ++p) {
        const int rp = r0 + p * 128;

        f32x4 acc[NFRAG];
#pragma unroll
        for (int nf = 0; nf < NFRAG; ++nf) acc[nf] = (f32x4){0.f, 0.f, 0.f, 0.f};
        float den = 0.f;

#pragma unroll
        for (int kk = 0; kk < KK_STEPS; ++kk) {
            const int g    = p * KK_STEPS + kk;      // global iteration 0..31
            const int slot = g % PF_DEPTH;           // compile-time constant
            f32x4 s0 = sbuf[slot][0];
            f32x4 s1 = sbuf[slot][1];
            // refill this slot for global iteration g+6 (possibly next panel)
            if (g + PF_DEPTH < 2 * KK_STEPS) {
                const int   f  = g + PF_DEPTH;
                const float* b = (f < KK_STEPS) ? sp0 : sp1;
                const int   tk = f & (KK_STEPS - 1);
                sbuf[slot][0] = *reinterpret_cast<const f32x4*>(b + tk * 32);
                sbuf[slot][1] = *reinterpret_cast<const f32x4*>(b + tk * 32 + 4);
            }
            float e0 = __expf(s0[0]), e1 = __expf(s0[1]);
            float e2 = __expf(s0[2]), e3 = __expf(s0[3]);
            float e4 = __expf(s1[0]), e5 = __expf(s1[1]);
            float e6 = __expf(s1[2]), e7 = __expf(s1[3]);
            den += ((e0 + e1) + (e2 + e3)) + ((e4 + e5) + (e6 + e7));
            i32x4 aw;
            aw[0] = cvt_pk_bf16(e0, e1);
            aw[1] = cvt_pk_bf16(e2, e3);
            aw[2] = cvt_pk_bf16(e4, e5);
            aw[3] = cvt_pk_bf16(e6, e7);
            bf16x8 av = __builtin_bit_cast(bf16x8, aw);
#pragma unroll
            for (int nf = 0; nf < NFRAG; ++nf) {
                bf16x8 bv = __builtin_bit_cast(bf16x8, bsh[(kk * NFRAG + nf) * 64 + l]);
                acc[nf] = __builtin_amdgcn_mfma_f32_16x16x32_bf16(av, bv, acc[nf], 0, 0, 0);
            }
            if (g & 1) __builtin_amdgcn_sched_barrier(0);  // fence every 2 iters
        }

        // den(l) holds row lmod's partial over k-chunk lh: reduce the 4 chunks.
        den += __shfl_xor(den, 16, 64);
        den += __shfl_xor(den, 32, 64);
        // C/D layout: col = lane&15 (-> d), row = 4*(lane>>4)+reg (-> t).
        float inv[4];
#pragma unroll
        for (int r = 0; r < 4; ++r)
            inv[r] = 1.0f / __shfl(den, 4 * lh + r, 64);

#pragma unroll
        for (int nf = 0; nf < NFRAG; ++nf) {
            f32x4 v;
#pragma unroll
            for (int r = 0; r < 4; ++r) v[r] = acc[nf][r] * inv[r];
            *reinterpret_cast<f32x4*>(out + (size_t)(d0 + nf * 16 + lmod) * T_DIM
                                      + rp + 4 * lh) = v;
        }
    }
}

extern "C" void kernel_launch(void* const* d_in, const int* in_sizes, int n_in,
                              void* d_out, int out_size, void* d_ws, size_t ws_size,
                              hipStream_t stream) {
    const float* u = (const float*)d_in[0];   // (1, 512, 128) fp32
    const float* s = (const float*)d_in[1];   // (65536, 512) fp32
    float* out = (float*)d_out;               // (128, 65536) fp32

    c2q_main<<<2 * (T_DIM / 256), 512, 0, stream>>>(s, u, out);
}

// Round 13
// 54.518 us; speedup vs baseline: 1.2403x; 1.2403x over previous
//
#include <hip/hip_runtime.h>
#include <hip/hip_bf16.h>

// out[d,t] = (sum_j exp(s[t,j]) * u[j,d]) / (sum_j exp(s[t,j]))
// Fused exp-GEMM, B staged in LDS.
// R13: D-split geometry (each block: half of D = 4 N-frags x 256 rows, 64KB
// LDS -> 2 blocks/CU -> 4 waves/SIMD) carried by R9's PROVEN conservative
// body: manual f2bf_rne pack (pure SSA bit-ops, no inline asm to reorder
// around) and sched_barrier(0) EVERY iteration. R12's failure (absmax 0.31,
// identical math, only bounds differed from passing R11) is attributed to a
// codegen hazard around inline-asm cvt_pk + relaxed fences — both removed.
// launch_bounds(512,2): the only config that has never spilled (R4/R8/R9/R10).

constexpr int T_DIM = 65536;
constexpr int J_DIM = 512;
constexpr int D_DIM = 128;
constexpr int KK_STEPS = J_DIM / 32;   // 16
constexpr int NFRAG = 4;               // 4 N-fragments = 64 of 128 d-cols
constexpr int PF_DEPTH = 6;            // s-load prefetch depth (iterations)
constexpr int BP_ELEMS = KK_STEPS * NFRAG * 64;   // s16x8 elements = 4096 (64KB)

typedef __attribute__((ext_vector_type(4))) float  f32x4;
typedef __attribute__((ext_vector_type(8))) short  s16x8;
typedef __attribute__((ext_vector_type(8))) __bf16 bf16x8;

__device__ __forceinline__ short f2bf_rne(float f) {
    unsigned u = __builtin_bit_cast(unsigned, f);
    u += 0x7fffu + ((u >> 16) & 1u);   // round-to-nearest-even
    return (short)(u >> 16);
}

__global__ __launch_bounds__(512, 2) void c2q_main(const float* __restrict__ sm,
                                                   const float* __restrict__ u,
                                                   float* __restrict__ out) {
    __shared__ s16x8 bsh[BP_ELEMS];    // [kk][nf][lane] — 65536 bytes

    const int tid  = threadIdx.x;
    const int l    = tid & 63;
    const int w    = tid >> 6;        // wave 0..7
    const int lmod = l & 15;
    const int lh   = l >> 4;          // 0..3
    const int bid  = blockIdx.x;
    const int h    = bid >> 8;        // d-half 0/1   (bid = h*256 + rg)
    const int rg   = bid & 255;       // row-group
    const int d0   = h * 64;
    const int r0   = rg * 256 + w * 16;          // panel-0 first t-row

    // A-fragment sources: lane holds row r0+lmod, k = kk*32 + 8*lh + i.
    const float* sp0 = sm + (size_t)(r0 + lmod) * J_DIM + lh * 8;
    const float* sp1 = sp0 + 128 * J_DIM;        // panel-1 (r0+128)

    // ---- prologue: prefetch global iterations 0..5 (panel 0, kk 0..5) ----
    f32x4 sbuf[PF_DEPTH][2];
#pragma unroll
    for (int p = 0; p < PF_DEPTH; ++p) {
        sbuf[p][0] = *reinterpret_cast<const f32x4*>(sp0 + p * 32);
        sbuf[p][1] = *reinterpret_cast<const f32x4*>(sp0 + p * 32 + 4);
    }

    // ---- B gather-fill straight from u (L2-resident), this block's d-half ----
    // element e: lane=e&63, nf=(e>>6)&3, kk=e>>8;
    //   d = d0 + nf*16 + (e&15), k0 = kk*32 + 8*((e>>4)&3); pack 8 bf16.
#pragma unroll 4
    for (int it = 0; it < BP_ELEMS / 512; ++it) {
        int e  = it * 512 + tid;
        int d  = d0 + ((e >> 6) & (NFRAG - 1)) * 16 + (e & 15);
        int k0 = (e >> 8) * 32 + 8 * ((e >> 4) & 3);
        const float* up = u + (size_t)k0 * D_DIM + d;
        s16x8 o;
#pragma unroll
        for (int i = 0; i < 8; ++i)
            o[i] = f2bf_rne(up[(size_t)i * D_DIM]);
        bsh[e] = o;
    }
    __syncthreads();

#pragma unroll
    for (int p = 0; p < 2; ++p) {
        const int rp = r0 + p * 128;

        f32x4 acc[NFRAG];
#pragma unroll
        for (int nf = 0; nf < NFRAG; ++nf) acc[nf] = (f32x4){0.f, 0.f, 0.f, 0.f};
        float den = 0.f;

#pragma unroll
        for (int kk = 0; kk < KK_STEPS; ++kk) {
            const int g    = p * KK_STEPS + kk;      // global iteration 0..31
            const int slot = g % PF_DEPTH;           // compile-time constant
            f32x4 s0 = sbuf[slot][0];
            f32x4 s1 = sbuf[slot][1];
            // refill this slot for global iteration g+6 (possibly next panel)
            if (g + PF_DEPTH < 2 * KK_STEPS) {
                const int   f  = g + PF_DEPTH;
                const float* b = (f < KK_STEPS) ? sp0 : sp1;
                const int   tk = f & (KK_STEPS - 1);
                sbuf[slot][0] = *reinterpret_cast<const f32x4*>(b + tk * 32);
                sbuf[slot][1] = *reinterpret_cast<const f32x4*>(b + tk * 32 + 4);
            }
            float e0 = __expf(s0[0]), e1 = __expf(s0[1]);
            float e2 = __expf(s0[2]), e3 = __expf(s0[3]);
            float e4 = __expf(s1[0]), e5 = __expf(s1[1]);
            float e6 = __expf(s1[2]), e7 = __expf(s1[3]);
            den += ((e0 + e1) + (e2 + e3)) + ((e4 + e5) + (e6 + e7));
            s16x8 a;
            a[0] = f2bf_rne(e0); a[1] = f2bf_rne(e1);
            a[2] = f2bf_rne(e2); a[3] = f2bf_rne(e3);
            a[4] = f2bf_rne(e4); a[5] = f2bf_rne(e5);
            a[6] = f2bf_rne(e6); a[7] = f2bf_rne(e7);
            bf16x8 av = __builtin_bit_cast(bf16x8, a);
#pragma unroll
            for (int nf = 0; nf < NFRAG; ++nf) {
                bf16x8 bv = __builtin_bit_cast(bf16x8, bsh[(kk * NFRAG + nf) * 64 + l]);
                acc[nf] = __builtin_amdgcn_mfma_f32_16x16x32_bf16(av, bv, acc[nf], 0, 0, 0);
            }
            __builtin_amdgcn_sched_barrier(0);   // fence EVERY iteration (R9)
        }

        // den(l) holds row lmod's partial over k-chunk lh: reduce the 4 chunks.
        den += __shfl_xor(den, 16, 64);
        den += __shfl_xor(den, 32, 64);
        // C/D layout: col = lane&15 (-> d), row = 4*(lane>>4)+reg (-> t).
        float inv[4];
#pragma unroll
        for (int r = 0; r < 4; ++r)
            inv[r] = 1.0f / __shfl(den, 4 * lh + r, 64);

#pragma unroll
        for (int nf = 0; nf < NFRAG; ++nf) {
            f32x4 v;
#pragma unroll
            for (int r = 0; r < 4; ++r) v[r] = acc[nf][r] * inv[r];
            *reinterpret_cast<f32x4*>(out + (size_t)(d0 + nf * 16 + lmod) * T_DIM
                                      + rp + 4 * lh) = v;
        }
    }
}

extern "C" void kernel_launch(void* const* d_in, const int* in_sizes, int n_in,
                              void* d_out, int out_size, void* d_ws, size_t ws_size,
                              hipStream_t stream) {
    const float* u = (const float*)d_in[0];   // (1, 512, 128) fp32
    const float* s = (const float*)d_in[1];   // (65536, 512) fp32
    float* out = (float*)d_out;               // (128, 65536) fp32

    c2q_main<<<2 * (T_DIM / 256), 512, 0, stream>>>(s, u, out);
}